// Round 5
// baseline (381.952 us; speedup 1.0000x reference)
//
#include <hip/hip_runtime.h>

// Problem constants (B,S,D fixed by setup_inputs)
#define B_ 16
#define S_ 2048
#define D_ 128
#define C2 0.12751744f  // log2(e)/sqrt(128): exp(s/sqrt(d)) == exp2(s*C2)

typedef __attribute__((ext_vector_type(8))) short short8;   // 8 bf16 (4 VGPRs)
typedef __attribute__((ext_vector_type(4))) float f32x4;    // MFMA C/D

// LDS leading dims
#define KQ_LD 136   // 128 + 8 (16B-aligned rows)
#define VP_LD 72    // 64 + 8  (16B-aligned rows -> direct b128 V-frag reads)
#define PP_LD 72    // 64 + 8  (16B-aligned rows for b128 A-frag reads)
#define TR_LD 136   // prep transpose tile

// Workspace layout (bf16 elements), requires ws_size >= 24 MB:
//   Qbf [16][2048][128]          @ 0
//   Kbf [16][2048][128]          @ 4.2M elems
//   VT  [16][32][128][64] tiled  @ 8.4M elems (tile t = V rows t*64..t*64+63, transposed)
#define QBF_OFF 0
#define KBF_OFF (B_ * S_ * D_)
#define VT_OFF  (2 * B_ * S_ * D_)

__device__ __forceinline__ float fexp2(float x) {
#if __has_builtin(__builtin_amdgcn_exp2f)
    return __builtin_amdgcn_exp2f(x);
#else
    return exp2f(x);
#endif
}
__device__ __forceinline__ unsigned pack2(float a, float b) {
    union { float f; unsigned u; } x, y; x.f = a; y.f = b;
    unsigned ua = x.u + 0x7fffu + ((x.u >> 16) & 1u);  // RNE
    unsigned ub = y.u + 0x7fffu + ((y.u >> 16) & 1u);
    return (ua >> 16) | (ub & 0xffff0000u);
}

// LDS-only barrier: lgkmcnt(0) + s_barrier. Global loads/stores stay in
// flight (only cross-wave hazards are LDS: sQ/sV/sP/sL).
__device__ __forceinline__ void ldsbar() {
    asm volatile("s_waitcnt lgkmcnt(0)" ::: "memory");
    __builtin_amdgcn_s_barrier();
    asm volatile("" ::: "memory");
}

// ===================== prep: fp32 -> bf16 (+ V transpose) =====================
// One-time conversion so the hot kernel never runs pack VALU in its loop and
// reads half the bytes. RNE here == pack2 in the old staging -> bit-identical.
__global__ __launch_bounds__(256, 2)
void prep_kernel(const float* __restrict__ Qg, const float* __restrict__ Kg,
                 const float* __restrict__ Vg, unsigned short* __restrict__ ws)
{
    __shared__ unsigned short sT[64 * TR_LD];
    const int tid = threadIdx.x;
    const int b   = blockIdx.x >> 5;   // batch
    const int t   = blockIdx.x & 31;   // 64-row tile
    const int i0  = t * 64;
    const int rt  = tid >> 5;          // 0..7
    const int ct  = (tid & 31) * 4;    // 0..124

    const float* Qb = Qg + (size_t)b * S_ * D_;
    const float* Kb = Kg + (size_t)b * S_ * D_;
    const float* Vb = Vg + (size_t)b * S_ * D_;
    unsigned short* Qo = ws + QBF_OFF + (size_t)b * S_ * D_;
    unsigned short* Ko = ws + KBF_OFF + (size_t)b * S_ * D_;
    unsigned short* Vo = ws + VT_OFF + (size_t)(b * 32 + t) * D_ * 64;

#pragma unroll
    for (int p = 0; p < 8; ++p) {
        const int row = i0 + p * 8 + rt;
        const float4 q = *(const float4*)(Qb + (size_t)row * D_ + ct);
        const float4 k = *(const float4*)(Kb + (size_t)row * D_ + ct);
        *(uint2*)&Qo[(size_t)row * D_ + ct] = make_uint2(pack2(q.x,q.y), pack2(q.z,q.w));
        *(uint2*)&Ko[(size_t)row * D_ + ct] = make_uint2(pack2(k.x,k.y), pack2(k.z,k.w));
    }
    // V: coalesced read -> bf16 tile [i][d] in LDS -> coalesced transposed write
#pragma unroll
    for (int p = 0; p < 8; ++p) {
        const float4 v = *(const float4*)(Vb + (size_t)(i0 + p * 8 + rt) * D_ + ct);
        *(uint2*)&sT[(p * 8 + rt) * TR_LD + ct] = make_uint2(pack2(v.x,v.y), pack2(v.z,v.w));
    }
    __syncthreads();
    const int d = tid >> 1;           // 0..127
    const int h = (tid & 1) * 32;     // i-half
    unsigned short tmp[32];
#pragma unroll
    for (int k2 = 0; k2 < 32; ++k2)
        tmp[k2] = sT[(h + k2) * TR_LD + d];
#pragma unroll
    for (int k2 = 0; k2 < 4; ++k2)
        *(uint4*)&Vo[(size_t)d * 64 + h + k2 * 8] = *(uint4*)&tmp[k2 * 8];
}

// ============================== main attention ===============================
__global__ __launch_bounds__(256, 2)
void attn_kernel(const unsigned short* __restrict__ Qbf,
                 const unsigned short* __restrict__ Kbf,
                 const unsigned short* __restrict__ VTg,
                 float* __restrict__ out)
{
    // A = Q rows (i), B = K rows (j). C layout: col(lane&15)=j,
    // row(quad*4+g)=i -> lane holds 4 consecutive i at fixed j.
    __shared__ unsigned short sQ[2][64 * KQ_LD];   // A operand: Q rows (i)
    __shared__ unsigned short sV[2][128 * VP_LD];  // B operand for PV: sV[d][i]
    __shared__ unsigned short sP[64 * PP_LD];      // A operand for PV
    __shared__ float sL[2][64];                    // cross-wave row-sum reduce

    const int tid  = threadIdx.x;
    const int lane = tid & 63;
    const int wv   = tid >> 6;
    const int wr   = wv >> 1;      // i-half owner
    const int wc   = wv & 1;       // j-half owner
    const int quad = lane >> 4;
    const int lo   = lane & 15;

    // XCD-aware mapping: XCD x owns batches {2x,2x+1}; balanced 33 iters/CU.
    const int x     = blockIdx.x & 7;
    const int k     = blockIdx.x >> 3;
    const int slot  = k & 31;
    const int wave2 = k >> 5;
    const int b     = 2 * x + wave2;
    const int jt    = wave2 ? (31 - slot) : slot;
    const int j0    = jt * 64;

    const unsigned short* Qb  = Qbf + (size_t)b * S_ * D_;
    const unsigned short* Kb  = Kbf + (size_t)b * S_ * D_;
    const unsigned short* VTb = VTg + (size_t)b * 32 * D_ * 64;
    float* Ob = out + (size_t)b * S_ * D_;
    float* Wb = out + (size_t)B_ * S_ * D_ + (size_t)b * S_ * S_;

    const int rt = tid >> 5;         // 0..7
    const int ct = (tid & 31) * 4;   // 0..124

    // ---- K fragments -> registers (once; direct bf16, no conversion) ----
    short8 kf0[4], kf1[4];
    {
        const unsigned short* kr = Kb + (size_t)(j0 + wc * 32 + lo) * D_ + quad * 8;
#pragma unroll
        for (int ks = 0; ks < 4; ++ks) {
            kf0[ks] = *(const short8*)(kr + ks * 32);
            kf1[ks] = *(const short8*)(kr + (size_t)16 * D_ + ks * 32);
        }
    }

    // ================= pass 1: l_j = sum_i exp(s), 1 barrier/iter =========
    float lpart[2] = {0.f, 0.f};
    uint2 qpre[8];
#pragma unroll
    for (int p = 0; p < 8; ++p)
        qpre[p] = *(const uint2*)(Qb + (size_t)(jt * 64 + p * 8 + rt) * D_ + ct);

    for (int it = jt; it < 32; ++it) {
        unsigned short* sQb = sQ[(it - jt) & 1];
        // pure copy staging: no conversion VALU
#pragma unroll
        for (int p = 0; p < 8; ++p)
            *(uint2*)&sQb[(p * 8 + rt) * KQ_LD + ct] = qpre[p];
        ldsbar();   // staging visible; only barrier this iteration

        if (it + 1 < 32) {
#pragma unroll
            for (int p = 0; p < 8; ++p)
                qpre[p] = *(const uint2*)(Qb + (size_t)((it + 1) * 64 + p * 8 + rt) * D_ + ct);
        }

        f32x4 acc[2][2];
#pragma unroll
        for (int r = 0; r < 2; ++r)
#pragma unroll
            for (int c = 0; c < 2; ++c)
                acc[r][c] = (f32x4){0.f, 0.f, 0.f, 0.f};

        const unsigned short* pA = &sQb[(wr * 32 + lo) * KQ_LD];
#pragma unroll
        for (int ks = 0; ks < 4; ++ks) {
            const int ko = ks * 32 + quad * 8;
            short8 a0 = *(const short8*)(pA + ko);
            short8 a1 = *(const short8*)(pA + 16 * KQ_LD + ko);
            acc[0][0] = __builtin_amdgcn_mfma_f32_16x16x32_bf16(a0, kf0[ks], acc[0][0], 0, 0, 0);
            acc[0][1] = __builtin_amdgcn_mfma_f32_16x16x32_bf16(a0, kf1[ks], acc[0][1], 0, 0, 0);
            acc[1][0] = __builtin_amdgcn_mfma_f32_16x16x32_bf16(a1, kf0[ks], acc[1][0], 0, 0, 0);
            acc[1][1] = __builtin_amdgcn_mfma_f32_16x16x32_bf16(a1, kf1[ks], acc[1][1], 0, 0, 0);
        }

        if (it == jt) {  // diagonal tile: keep i >= j
#pragma unroll
            for (int r = 0; r < 2; ++r)
#pragma unroll
                for (int c = 0; c < 2; ++c)
#pragma unroll
                    for (int g = 0; g < 4; ++g) {
                        const int ii = wr * 32 + r * 16 + quad * 4 + g;
                        const int jj = wc * 32 + c * 16 + lo;
                        lpart[c] += (ii >= jj) ? fexp2(acc[r][c][g] * C2) : 0.f;
                    }
        } else {
#pragma unroll
            for (int r = 0; r < 2; ++r)
#pragma unroll
                for (int c = 0; c < 2; ++c)
#pragma unroll
                    for (int g = 0; g < 4; ++g)
                        lpart[c] += fexp2(acc[r][c][g] * C2);
        }
    }

    // i-direction spans quads: butterfly over quads, then cross-wave via sL
#pragma unroll
    for (int c = 0; c < 2; ++c) {
        float v = lpart[c];
        v += __shfl_xor(v, 16);
        v += __shfl_xor(v, 32);
        if (quad == 0) sL[wr][wc * 32 + c * 16 + lo] = v;
    }
    ldsbar();
    float rl[2];
#pragma unroll
    for (int c = 0; c < 2; ++c) {
        const int jj = wc * 32 + c * 16 + lo;
        rl[c] = 1.0f / (sL[0][jj] + sL[1][jj]);
    }

    // ---- zero-fill fully-masked region: cols [0, j0), nontemporal ----
    {
        const f32x4 z = {0.f, 0.f, 0.f, 0.f};
        for (int c0 = tid * 4; c0 < j0; c0 += 1024) {
            float* base = Wb + (size_t)j0 * S_ + c0;
            for (int r = 0; r < 64; ++r) {
                __builtin_nontemporal_store(z, (f32x4*)base);
                base += S_;
            }
        }
    }

    // ================= pass 2: w writes + O = W*V, 2 barriers/iter ========
    f32x4 acc_o[2][4];
#pragma unroll
    for (int r = 0; r < 2; ++r)
#pragma unroll
        for (int c = 0; c < 4; ++c)
            acc_o[r][c] = (f32x4){0.f, 0.f, 0.f, 0.f};

    const int vd = tid >> 1;          // 0..127 (d)
    const int vh = (tid & 1) * 32;    // i-half within tile

    uint4 vpre[4];
#pragma unroll
    for (int k2 = 0; k2 < 4; ++k2)
        vpre[k2] = *(const uint4*)(VTb + (size_t)jt * D_ * 64 + (size_t)vd * 64 + vh + k2 * 8);
#pragma unroll
    for (int p = 0; p < 8; ++p)
        qpre[p] = *(const uint2*)(Qb + (size_t)(jt * 64 + p * 8 + rt) * D_ + ct);

    for (int it = jt; it < 32; ++it) {
        const int cur = (it - jt) & 1;
        unsigned short* sQb = sQ[cur];
        unsigned short* sVb = sV[cur];

        // pure-copy staging of current tiles (no conversion VALU)
#pragma unroll
        for (int p = 0; p < 8; ++p)
            *(uint2*)&sQb[(p * 8 + rt) * KQ_LD + ct] = qpre[p];
#pragma unroll
        for (int k2 = 0; k2 < 4; ++k2)
            *(uint4*)&sVb[vd * VP_LD + vh + k2 * 8] = vpre[k2];
        ldsbar();  // B: staging visible (also drains PV(it-1)'s sP/sV reads)

        if (it + 1 < 32) {  // prefetch next Q and V tiles (bf16, coalesced)
#pragma unroll
            for (int p = 0; p < 8; ++p)
                qpre[p] = *(const uint2*)(Qb + (size_t)((it + 1) * 64 + p * 8 + rt) * D_ + ct);
#pragma unroll
            for (int k2 = 0; k2 < 4; ++k2)
                vpre[k2] = *(const uint4*)(VTb + (size_t)(it + 1) * D_ * 64 + (size_t)vd * 64 + vh + k2 * 8);
        }

        // QK^T: A-frags from LDS, K from registers
        f32x4 acc[2][2];
#pragma unroll
        for (int r = 0; r < 2; ++r)
#pragma unroll
            for (int c = 0; c < 2; ++c)
                acc[r][c] = (f32x4){0.f, 0.f, 0.f, 0.f};

        const unsigned short* pA = &sQb[(wr * 32 + lo) * KQ_LD];
#pragma unroll
        for (int ks = 0; ks < 4; ++ks) {
            const int ko = ks * 32 + quad * 8;
            short8 a0 = *(const short8*)(pA + ko);
            short8 a1 = *(const short8*)(pA + 16 * KQ_LD + ko);
            acc[0][0] = __builtin_amdgcn_mfma_f32_16x16x32_bf16(a0, kf0[ks], acc[0][0], 0, 0, 0);
            acc[0][1] = __builtin_amdgcn_mfma_f32_16x16x32_bf16(a0, kf1[ks], acc[0][1], 0, 0, 0);
            acc[1][0] = __builtin_amdgcn_mfma_f32_16x16x32_bf16(a1, kf0[ks], acc[1][0], 0, 0, 0);
            acc[1][1] = __builtin_amdgcn_mfma_f32_16x16x32_bf16(a1, kf1[ks], acc[1][1], 0, 0, 0);
        }

        if (it == jt) {
#pragma unroll
            for (int r = 0; r < 2; ++r)
#pragma unroll
                for (int c = 0; c < 2; ++c) {
                    const int jj = wc * 32 + c * 16 + lo;        // W row (local)
                    const int ib = wr * 32 + r * 16 + quad * 4;  // W col base
                    f32x4 w;
#pragma unroll
                    for (int g = 0; g < 4; ++g) {
                        const float pw = (ib + g >= jj) ? fexp2(acc[r][c][g] * C2) : 0.f;
                        w[g] = pw * rl[c];
                    }
                    __builtin_nontemporal_store(w,
                        (f32x4*)(Wb + (size_t)(j0 + jj) * S_ + (size_t)(it * 64 + ib)));
                    *(uint2*)&sP[jj * PP_LD + ib] =
                        make_uint2(pack2(w[0], w[1]), pack2(w[2], w[3]));
                }
        } else {
#pragma unroll
            for (int r = 0; r < 2; ++r)
#pragma unroll
                for (int c = 0; c < 2; ++c) {
                    const int jj = wc * 32 + c * 16 + lo;
                    const int ib = wr * 32 + r * 16 + quad * 4;
                    f32x4 w;
#pragma unroll
                    for (int g = 0; g < 4; ++g)
                        w[g] = fexp2(acc[r][c][g] * C2) * rl[c];
                    __builtin_nontemporal_store(w,
                        (f32x4*)(Wb + (size_t)(j0 + jj) * S_ + (size_t)(it * 64 + ib)));
                    *(uint2*)&sP[jj * PP_LD + ib] =
                        make_uint2(pack2(w[0], w[1]), pack2(w[2], w[3]));
                }
        }
        ldsbar();  // C: sP visible (single-buffer sP: WAR covered by next B)

        // O += W(64x64) * V(64x128); wave does 32(j) x 64(d)
        const unsigned short* pP = &sP[(wr * 32 + lo) * PP_LD];
        const unsigned short* pV = &sVb[(wc * 64 + lo) * VP_LD];
#pragma unroll
        for (int ks = 0; ks < 2; ++ks) {
            const int ko = ks * 32 + quad * 8;
            short8 a0 = *(const short8*)(pP + ko);
            short8 a1 = *(const short8*)(pP + 16 * PP_LD + ko);
#pragma unroll
            for (int c2 = 0; c2 < 4; ++c2) {
                short8 bv = *(const short8*)(pV + c2 * 16 * VP_LD + ko);  // b128 (16B-aligned rows)
                acc_o[0][c2] = __builtin_amdgcn_mfma_f32_16x16x32_bf16(a0, bv, acc_o[0][c2], 0, 0, 0);
                acc_o[1][c2] = __builtin_amdgcn_mfma_f32_16x16x32_bf16(a1, bv, acc_o[1][c2], 0, 0, 0);
            }
        }
    }

    // ---- write outputs O (64 x 128 fp32), nontemporal ----
#pragma unroll
    for (int r = 0; r < 2; ++r)
#pragma unroll
        for (int c2 = 0; c2 < 4; ++c2)
#pragma unroll
            for (int g = 0; g < 4; ++g) {
                const int jr = wr * 32 + r * 16 + quad * 4 + g;
                const int dc = wc * 64 + c2 * 16 + lo;
                __builtin_nontemporal_store(acc_o[r][c2][g],
                                            Ob + (size_t)(j0 + jr) * D_ + dc);
            }
}

extern "C" void kernel_launch(void* const* d_in, const int* in_sizes, int n_in,
                              void* d_out, int out_size, void* d_ws, size_t ws_size,
                              hipStream_t stream) {
    const float* Q = (const float*)d_in[0];
    const float* K = (const float*)d_in[1];
    const float* V = (const float*)d_in[2];
    float* out = (float*)d_out;
    unsigned short* ws = (unsigned short*)d_ws;   // needs >= 24 MB
    (void)in_sizes; (void)n_in; (void)out_size; (void)ws_size;
    hipLaunchKernelGGL(prep_kernel, dim3(512), dim3(256), 0, stream, Q, K, V, ws);
    hipLaunchKernelGGL(attn_kernel, dim3(16 * 32), dim3(256), 0, stream,
                       ws + QBF_OFF, ws + KBF_OFF, ws + VT_OFF, out);
}

// Round 6
// 358.719 us; speedup vs baseline: 1.0648x; 1.0648x over previous
//
#include <hip/hip_runtime.h>

// Problem constants (B,S,D fixed by setup_inputs)
#define B_ 16
#define S_ 2048
#define D_ 128
#define C2 0.12751744f  // log2(e)/sqrt(128): exp(s/sqrt(d)) == exp2(s*C2)

typedef __attribute__((ext_vector_type(8))) short short8;   // 8 bf16 (4 VGPRs)
typedef __attribute__((ext_vector_type(4))) short short4v;  // 4 bf16 (2 VGPRs)
typedef __attribute__((ext_vector_type(4))) float f32x4;    // MFMA C/D

// LDS leading dims
#define KQ_LD 136   // 128 + 8 (16B-aligned rows)
#define VP_LD 68    // 64 + 4  (8B-aligned rows)
#define PP_LD 72    // 64 + 8  (16B-aligned rows for b128 A-frag reads)

__device__ __forceinline__ float fexp2(float x) {
#if __has_builtin(__builtin_amdgcn_exp2f)
    return __builtin_amdgcn_exp2f(x);
#else
    return exp2f(x);
#endif
}
__device__ __forceinline__ unsigned pack2(float a, float b) {
    union { float f; unsigned u; } x, y; x.f = a; y.f = b;
    unsigned ua = x.u + 0x7fffu + ((x.u >> 16) & 1u);  // RNE
    unsigned ub = y.u + 0x7fffu + ((y.u >> 16) & 1u);
    return (ua >> 16) | (ub & 0xffff0000u);
}
// 8 fp32 -> short8 bf16 (same RNE as pack2 -> bit-identical to staged path)
__device__ __forceinline__ short8 pack8(float4 a, float4 b) {
    union { unsigned u[4]; short8 s; } r;
    r.u[0] = pack2(a.x, a.y); r.u[1] = pack2(a.z, a.w);
    r.u[2] = pack2(b.x, b.y); r.u[3] = pack2(b.z, b.w);
    return r.s;
}
__device__ __forceinline__ short8 ldsV8(const unsigned short* p) {
    short4v a = *(const short4v*)p;
    short4v b = *(const short4v*)(p + 4);
    return __builtin_shufflevector(a, b, 0, 1, 2, 3, 4, 5, 6, 7);
}

// LDS-only barrier: lgkmcnt(0) + s_barrier. Global loads/stores stay in
// flight (only cross-wave hazards are LDS: sQ/sV/sP/sL).
__device__ __forceinline__ void ldsbar() {
    asm volatile("s_waitcnt lgkmcnt(0)" ::: "memory");
    __builtin_amdgcn_s_barrier();
    asm volatile("" ::: "memory");
}

__global__ __launch_bounds__(256, 2)
void attn_kernel(const float* __restrict__ Qg, const float* __restrict__ Kg,
                 const float* __restrict__ Vg, float* __restrict__ out)
{
    // A = Q rows (i), B = K rows (j). C layout: col(lane&15)=j,
    // row(quad*4+g)=i -> lane holds 4 consecutive i at fixed j.
    //
    // Round-5 theory: W/O writes were NONTEMPORAL 64B partial-line scatter
    // (NT bypasses L2 write-allocate -> partial lines hit the fabric; R2
    // counters showed WRITE_SIZE 378MB vs 285MB logical). Fix: regular
    // stores (L2 write-combine) + issue both 64B halves of each 128B line
    // back-to-back (r-inner loops). Zero-fill stays NT (full-line bursts).
    __shared__ unsigned short sQ[2][64 * KQ_LD];   // A operand: Q rows (i)
    __shared__ unsigned short sV[2][128 * VP_LD];  // B operand for PV: sV[d][i]
    __shared__ unsigned short sP[64 * PP_LD];      // A operand for PV
    __shared__ float sL[2][64];                    // cross-wave row-sum reduce

    const int tid  = threadIdx.x;
    const int lane = tid & 63;
    const int wv   = tid >> 6;
    const int wr   = wv >> 1;      // i-half owner
    const int wc   = wv & 1;       // j-half owner
    const int quad = lane >> 4;
    const int lo   = lane & 15;

    // XCD-aware mapping: XCD x owns batches {2x,2x+1}; balanced 33 iters/CU.
    const int x     = blockIdx.x & 7;
    const int k     = blockIdx.x >> 3;
    const int slot  = k & 31;
    const int wave2 = k >> 5;
    const int b     = 2 * x + wave2;
    const int jt    = wave2 ? (31 - slot) : slot;
    const int j0    = jt * 64;

    const float* Qb = Qg + (size_t)b * S_ * D_;
    const float* Kb = Kg + (size_t)b * S_ * D_;
    const float* Vb = Vg + (size_t)b * S_ * D_;
    float* Ob = out + (size_t)b * S_ * D_;
    float* Wb = out + (size_t)B_ * S_ * D_ + (size_t)b * S_ * S_;

    const int rt = tid >> 5;         // 0..7
    const int ct = (tid & 31) * 4;   // 0..124

    // ---- K fragments -> registers (once per block; loop-invariant) ----
    short8 kf0[4], kf1[4];
    {
        const float* kr = Kb + (size_t)(j0 + wc * 32 + lo) * D_ + quad * 8;
#pragma unroll
        for (int ks = 0; ks < 4; ++ks) {
            float4 x0 = *(const float4*)(kr + ks * 32);
            float4 x1 = *(const float4*)(kr + ks * 32 + 4);
            float4 y0 = *(const float4*)(kr + (size_t)16 * D_ + ks * 32);
            float4 y1 = *(const float4*)(kr + (size_t)16 * D_ + ks * 32 + 4);
            kf0[ks] = pack8(x0, x1);
            kf1[ks] = pack8(y0, y1);
        }
    }

    // ================= pass 1: l_j = sum_i exp(s), 1 barrier/iter =========
    float lpart[2] = {0.f, 0.f};
    float4 qpre[8];
#pragma unroll
    for (int p = 0; p < 8; ++p)
        qpre[p] = *(const float4*)(Qb + (size_t)(jt * 64 + p * 8 + rt) * D_ + ct);

    for (int it = jt; it < 32; ++it) {
        unsigned short* sQb = sQ[(it - jt) & 1];
#pragma unroll
        for (int p = 0; p < 8; ++p) {
            const float4 v = qpre[p];
            *(uint2*)&sQb[(p * 8 + rt) * KQ_LD + ct] =
                make_uint2(pack2(v.x, v.y), pack2(v.z, v.w));
        }
        ldsbar();   // staging visible; only barrier this iteration

        if (it + 1 < 32) {
#pragma unroll
            for (int p = 0; p < 8; ++p)
                qpre[p] = *(const float4*)(Qb + (size_t)((it + 1) * 64 + p * 8 + rt) * D_ + ct);
        }

        f32x4 acc[2][2];
#pragma unroll
        for (int r = 0; r < 2; ++r)
#pragma unroll
            for (int c = 0; c < 2; ++c)
                acc[r][c] = (f32x4){0.f, 0.f, 0.f, 0.f};

        const unsigned short* pA = &sQb[(wr * 32 + lo) * KQ_LD];
#pragma unroll
        for (int ks = 0; ks < 4; ++ks) {
            const int ko = ks * 32 + quad * 8;
            short8 a0 = *(const short8*)(pA + ko);
            short8 a1 = *(const short8*)(pA + 16 * KQ_LD + ko);
            acc[0][0] = __builtin_amdgcn_mfma_f32_16x16x32_bf16(a0, kf0[ks], acc[0][0], 0, 0, 0);
            acc[0][1] = __builtin_amdgcn_mfma_f32_16x16x32_bf16(a0, kf1[ks], acc[0][1], 0, 0, 0);
            acc[1][0] = __builtin_amdgcn_mfma_f32_16x16x32_bf16(a1, kf0[ks], acc[1][0], 0, 0, 0);
            acc[1][1] = __builtin_amdgcn_mfma_f32_16x16x32_bf16(a1, kf1[ks], acc[1][1], 0, 0, 0);
        }

        if (it == jt) {  // diagonal tile: keep i >= j
#pragma unroll
            for (int r = 0; r < 2; ++r)
#pragma unroll
                for (int c = 0; c < 2; ++c)
#pragma unroll
                    for (int g = 0; g < 4; ++g) {
                        const int ii = wr * 32 + r * 16 + quad * 4 + g;
                        const int jj = wc * 32 + c * 16 + lo;
                        lpart[c] += (ii >= jj) ? fexp2(acc[r][c][g] * C2) : 0.f;
                    }
        } else {
#pragma unroll
            for (int r = 0; r < 2; ++r)
#pragma unroll
                for (int c = 0; c < 2; ++c)
#pragma unroll
                    for (int g = 0; g < 4; ++g)
                        lpart[c] += fexp2(acc[r][c][g] * C2);
        }
    }

    // i-direction spans quads: butterfly over quads, then cross-wave via sL
#pragma unroll
    for (int c = 0; c < 2; ++c) {
        float v = lpart[c];
        v += __shfl_xor(v, 16);
        v += __shfl_xor(v, 32);
        if (quad == 0) sL[wr][wc * 32 + c * 16 + lo] = v;
    }
    ldsbar();
    float rl[2];
#pragma unroll
    for (int c = 0; c < 2; ++c) {
        const int jj = wc * 32 + c * 16 + lo;
        rl[c] = 1.0f / (sL[0][jj] + sL[1][jj]);
    }

    // ---- zero-fill fully-masked region: cols [0, j0), nontemporal ----
    // (full-line contiguous 1KB/wave bursts: NT is optimal here)
    {
        const f32x4 z = {0.f, 0.f, 0.f, 0.f};
        for (int c0 = tid * 4; c0 < j0; c0 += 1024) {
            float* base = Wb + (size_t)j0 * S_ + c0;
            for (int r = 0; r < 64; ++r) {
                __builtin_nontemporal_store(z, (f32x4*)base);
                base += S_;
            }
        }
    }

    // ================= pass 2: w writes + O = W*V, 2 barriers/iter ========
    f32x4 acc_o[2][4];
#pragma unroll
    for (int r = 0; r < 2; ++r)
#pragma unroll
        for (int c = 0; c < 4; ++c)
            acc_o[r][c] = (f32x4){0.f, 0.f, 0.f, 0.f};

    const int dcol = tid & 127;
    const int ih   = (tid >> 7) * 4;

    float vpre[8][4];
#pragma unroll
    for (int p = 0; p < 8; ++p) {
        const int i0l = p * 8 + ih;
#pragma unroll
        for (int q = 0; q < 4; ++q)
            vpre[p][q] = Vb[(size_t)(jt * 64 + i0l + q) * D_ + dcol];
    }
#pragma unroll
    for (int p = 0; p < 8; ++p)
        qpre[p] = *(const float4*)(Qb + (size_t)(jt * 64 + p * 8 + rt) * D_ + ct);

    for (int it = jt; it < 32; ++it) {
        const int cur = (it - jt) & 1;
        unsigned short* sQb = sQ[cur];
        unsigned short* sVb = sV[cur];

#pragma unroll
        for (int p = 0; p < 8; ++p) {
            const float4 v = qpre[p];
            *(uint2*)&sQb[(p * 8 + rt) * KQ_LD + ct] =
                make_uint2(pack2(v.x, v.y), pack2(v.z, v.w));
        }
#pragma unroll
        for (int p = 0; p < 8; ++p) {
            const int i0l = p * 8 + ih;
            *(uint2*)&sVb[dcol * VP_LD + i0l] =
                make_uint2(pack2(vpre[p][0], vpre[p][1]), pack2(vpre[p][2], vpre[p][3]));
        }
        ldsbar();  // B: staging visible (also drains PV(it-1)'s sP/sV reads)

        if (it + 1 < 32) {  // coalesced global prefetch of next Q and V tiles
#pragma unroll
            for (int p = 0; p < 8; ++p)
                qpre[p] = *(const float4*)(Qb + (size_t)((it + 1) * 64 + p * 8 + rt) * D_ + ct);
#pragma unroll
            for (int p = 0; p < 8; ++p) {
                const int i0l = p * 8 + ih;
#pragma unroll
                for (int q = 0; q < 4; ++q)
                    vpre[p][q] = Vb[(size_t)((it + 1) * 64 + i0l + q) * D_ + dcol];
            }
        }

        // QK^T: A-frags from LDS, K from registers
        f32x4 acc[2][2];
#pragma unroll
        for (int r = 0; r < 2; ++r)
#pragma unroll
            for (int c = 0; c < 2; ++c)
                acc[r][c] = (f32x4){0.f, 0.f, 0.f, 0.f};

        const unsigned short* pA = &sQb[(wr * 32 + lo) * KQ_LD];
#pragma unroll
        for (int ks = 0; ks < 4; ++ks) {
            const int ko = ks * 32 + quad * 8;
            short8 a0 = *(const short8*)(pA + ko);
            short8 a1 = *(const short8*)(pA + 16 * KQ_LD + ko);
            acc[0][0] = __builtin_amdgcn_mfma_f32_16x16x32_bf16(a0, kf0[ks], acc[0][0], 0, 0, 0);
            acc[0][1] = __builtin_amdgcn_mfma_f32_16x16x32_bf16(a0, kf1[ks], acc[0][1], 0, 0, 0);
            acc[1][0] = __builtin_amdgcn_mfma_f32_16x16x32_bf16(a1, kf0[ks], acc[1][0], 0, 0, 0);
            acc[1][1] = __builtin_amdgcn_mfma_f32_16x16x32_bf16(a1, kf1[ks], acc[1][1], 0, 0, 0);
        }

        // W store: c-outer, r-inner so the two 64B halves of each 128B line
        // (r=0: bytes [wr*128, +64), r=1: [+64, +128) of row jj) are issued
        // back-to-back as REGULAR stores -> TCC write-combines full lines.
        if (it == jt) {
#pragma unroll
            for (int c = 0; c < 2; ++c) {
                const int jj = wc * 32 + c * 16 + lo;        // W row (local)
                float* wrow = Wb + (size_t)(j0 + jj) * S_ + (size_t)(it * 64);
#pragma unroll
                for (int r = 0; r < 2; ++r) {
                    const int ib = wr * 32 + r * 16 + quad * 4;  // W col base
                    f32x4 w;
#pragma unroll
                    for (int g = 0; g < 4; ++g) {
                        const float pw = (ib + g >= jj) ? fexp2(acc[r][c][g] * C2) : 0.f;
                        w[g] = pw * rl[c];
                    }
                    *(f32x4*)(wrow + ib) = w;
                    *(uint2*)&sP[jj * PP_LD + ib] =
                        make_uint2(pack2(w[0], w[1]), pack2(w[2], w[3]));
                }
            }
        } else {
#pragma unroll
            for (int c = 0; c < 2; ++c) {
                const int jj = wc * 32 + c * 16 + lo;
                float* wrow = Wb + (size_t)(j0 + jj) * S_ + (size_t)(it * 64);
#pragma unroll
                for (int r = 0; r < 2; ++r) {
                    const int ib = wr * 32 + r * 16 + quad * 4;
                    f32x4 w;
#pragma unroll
                    for (int g = 0; g < 4; ++g)
                        w[g] = fexp2(acc[r][c][g] * C2) * rl[c];
                    *(f32x4*)(wrow + ib) = w;
                    *(uint2*)&sP[jj * PP_LD + ib] =
                        make_uint2(pack2(w[0], w[1]), pack2(w[2], w[3]));
                }
            }
        }
        ldsbar();  // C: sP visible (single-buffer sP: WAR covered by next B)

        // O += W(64x64) * V(64x128); wave does 32(j) x 64(d)
        const unsigned short* pP = &sP[(wr * 32 + lo) * PP_LD];
        const unsigned short* pV = &sVb[(wc * 64 + lo) * VP_LD];
#pragma unroll
        for (int ks = 0; ks < 2; ++ks) {
            const int ko = ks * 32 + quad * 8;
            short8 a0 = *(const short8*)(pP + ko);
            short8 a1 = *(const short8*)(pP + 16 * PP_LD + ko);
#pragma unroll
            for (int c2 = 0; c2 < 4; ++c2) {
                short8 bv = ldsV8(pV + c2 * 16 * VP_LD + ko);
                acc_o[0][c2] = __builtin_amdgcn_mfma_f32_16x16x32_bf16(a0, bv, acc_o[0][c2], 0, 0, 0);
                acc_o[1][c2] = __builtin_amdgcn_mfma_f32_16x16x32_bf16(a1, bv, acc_o[1][c2], 0, 0, 0);
            }
        }
    }

    // ---- write outputs O (64 x 128 fp32) ----
    // (r,g)-outer, c2-inner: 4 adjacent 64B segments = 256B/row, regular
    // stores so L2 write-combines.
#pragma unroll
    for (int r = 0; r < 2; ++r)
#pragma unroll
        for (int g = 0; g < 4; ++g) {
            const int jr = wr * 32 + r * 16 + quad * 4 + g;
            float* orow = Ob + (size_t)(j0 + jr) * D_ + wc * 64 + lo;
#pragma unroll
            for (int c2 = 0; c2 < 4; ++c2)
                orow[c2 * 16] = acc_o[r][c2][g];
        }
}

extern "C" void kernel_launch(void* const* d_in, const int* in_sizes, int n_in,
                              void* d_out, int out_size, void* d_ws, size_t ws_size,
                              hipStream_t stream) {
    const float* Q = (const float*)d_in[0];
    const float* K = (const float*)d_in[1];
    const float* V = (const float*)d_in[2];
    float* out = (float*)d_out;
    (void)in_sizes; (void)n_in; (void)out_size; (void)d_ws; (void)ws_size;
    hipLaunchKernelGGL(attn_kernel, dim3(16 * 32), dim3(256), 0, stream, Q, K, V, out);
}